// Round 8
// baseline (225.517 us; speedup 1.0000x reference)
//
#include <hip/hip_runtime.h>
#include <hip/hip_bf16.h>

#define N_NODES 50000
#define N_EDGES 500000
#define HDIM 128
#define HEADS 3
#define BB 512
#define LL 10
#define NEG_SLOPE 0.2f

typedef __hip_bfloat16 bf16;
typedef unsigned char fp8t;
typedef __bf16 v8bf __attribute__((ext_vector_type(8)));
typedef float f32x4 __attribute__((ext_vector_type(4)));

// ---------------- utility ----------------

__global__ void k_zero2(int* a, int na, int* b, int nb){
  int i = blockIdx.x*256 + threadIdx.x;
  if(i < na) a[i] = 0;
  if(i < nb) b[i] = 0;
}

__global__ void k_hist(const int* __restrict__ dst, int* __restrict__ cnt, int E){
  int e = blockIdx.x*256 + threadIdx.x;
  if(e < E) atomicAdd(&cnt[dst[e]], 1);
}

// ---------------- hierarchical scan: cnt[0..N) -> offs[0..N], offs[0]=0 ------

#define SCAN_TILE 2048
#define SCAN_NB ((N_NODES + SCAN_TILE - 1)/SCAN_TILE)   // 25

__global__ __launch_bounds__(256) void k_scan_part(const int* __restrict__ cnt,
                                                   int* __restrict__ bsum){
  int b = blockIdx.x, tid = threadIdx.x;
  int i0 = b*SCAN_TILE + tid*8;
  int s = 0;
  #pragma unroll
  for(int j = 0; j < 8; ++j){ int i = i0 + j; s += (i < N_NODES) ? cnt[i] : 0; }
  for(int m = 32; m; m >>= 1) s += __shfl_xor(s, m);
  __shared__ int ws[4];
  if((tid & 63) == 0) ws[tid >> 6] = s;
  __syncthreads();
  if(tid == 0) bsum[b] = ws[0] + ws[1] + ws[2] + ws[3];
}

__global__ __launch_bounds__(64) void k_scan_top(int* __restrict__ bsum, int nb){
  int tid = threadIdx.x;
  int v = (tid < nb) ? bsum[tid] : 0;
  for(int s = 1; s < 64; s <<= 1){
    int t = __shfl_up(v, s);
    if(tid >= s) v += t;
  }
  if(tid < nb) bsum[tid] = v;
}

__global__ __launch_bounds__(256) void k_scan_write(int* __restrict__ cnt,
                                                    const int* __restrict__ bsum,
                                                    int* __restrict__ offs){
  int b = blockIdx.x, tid = threadIdx.x;
  int lane = tid & 63, wv = tid >> 6;
  int i0 = b*SCAN_TILE + tid*8;
  int v[8]; int s = 0;
  #pragma unroll
  for(int j = 0; j < 8; ++j){
    int i = i0 + j;
    v[j] = (i < N_NODES) ? cnt[i] : 0;
    s += v[j];
  }
  #pragma unroll
  for(int j = 0; j < 8; ++j){ int i = i0 + j; if(i < N_NODES) cnt[i] = 0; }
  int incl = s;
  for(int sh = 1; sh < 64; sh <<= 1){
    int t = __shfl_up(incl, sh);
    if(lane >= sh) incl += t;
  }
  __shared__ int wtot[4];
  if(lane == 63) wtot[wv] = incl;
  __syncthreads();
  int woff = 0;
  for(int w = 0; w < wv; ++w) woff += wtot[w];
  int excl = woff + incl - s;
  int run = ((b > 0) ? bsum[b-1] : 0) + excl;
  #pragma unroll
  for(int j = 0; j < 8; ++j){
    int i = i0 + j;
    run += v[j];
    if(i < N_NODES) offs[i+1] = run;
  }
  if(b == 0 && tid == 0) offs[0] = 0;
}

__global__ void k_scatter(const int* __restrict__ src, const int* __restrict__ dst,
                          const int* __restrict__ offs, int* __restrict__ cur,
                          int* __restrict__ csr, int E){
  int e = blockIdx.x*256 + threadIdx.x;
  if(e < E){
    int d = dst[e];
    int p = offs[d] + atomicAdd(&cur[d], 1);
    if(p >= 0 && p < E) csr[p] = src[e];
  }
}

// ---------------- mark nodes whose h1 is actually consumed by layer 2 --------

__global__ __launch_bounds__(64) void k_mark(const int* __restrict__ nid,
                                             const int* __restrict__ offs,
                                             const int* __restrict__ csr,
                                             unsigned char* __restrict__ mark){
  unsigned n = (unsigned)nid[blockIdx.x];
  if(n >= N_NODES) return;
  if(threadIdx.x == 0) mark[n] = 1;
  int o0 = offs[n], o1 = offs[n+1];
  for(int j = o0 + (int)threadIdx.x; j < o1; j += 64){
    unsigned s = (unsigned)csr[j];
    if(s < N_NODES) mark[s] = 1;
  }
}

// ---------------- W transpose+convert: W f32 [128][384] -> Wt bf16 [384][128] -------

__global__ void k_wt(const float* __restrict__ W, bf16* __restrict__ Wt){
  int i = blockIdx.x*256 + threadIdx.x;
  if(i < HEADS*HDIM*HDIM){
    int n = i >> 7, k = i & 127;
    Wt[i] = __float2bfloat16(W[k*(HEADS*HDIM) + n]);
  }
}

// ---------------- GEMM + fused el/er + fp8 feat write ----------------

template<int AF32>
__global__ __launch_bounds__(256) void k_gemm(const void* __restrict__ Av,
                                              const bf16* __restrict__ Wt,
                                              const float* __restrict__ al,
                                              const float* __restrict__ ar,
                                              fp8t* __restrict__ feat8,
                                              float* __restrict__ el4,
                                              float* __restrict__ er4, int M){
  int tid  = threadIdx.x;
  int wave = tid >> 6, lane = tid & 63;
  int wr = wave >> 1, wc = wave & 1;
  int row0 = blockIdx.x*64 + wr*32;
  int col0 = blockIdx.y*128 + wc*64;
  int l15 = lane & 15, lhi = lane >> 4;

  f32x4 acc[2][4] = {};
  for(int kk = 0; kk < 4; ++kk){
    int kb = kk*32 + lhi*8;
    v8bf a[2], b[4];
    for(int mi = 0; mi < 2; ++mi){
      int r = row0 + mi*16 + l15;
      if(r >= M) r = M - 1;                 // clamp; stores are guarded
      if constexpr(AF32){
        const float* ap = (const float*)Av + (size_t)r*HDIM + kb;
        f32x4 lo = *reinterpret_cast<const f32x4*>(ap);
        f32x4 hi = *reinterpret_cast<const f32x4*>(ap + 4);
        #pragma unroll
        for(int j = 0; j < 4; ++j){ a[mi][j] = (__bf16)lo[j]; a[mi][4+j] = (__bf16)hi[j]; }
      } else {
        a[mi] = *reinterpret_cast<const v8bf*>((const bf16*)Av + (size_t)r*HDIM + kb);
      }
    }
    for(int ni = 0; ni < 4; ++ni){
      int c = col0 + ni*16 + l15;
      b[ni] = *reinterpret_cast<const v8bf*>(Wt + (size_t)c*HDIM + kb);
    }
    for(int mi = 0; mi < 2; ++mi)
      for(int ni = 0; ni < 4; ++ni)
        acc[mi][ni] = __builtin_amdgcn_mfma_f32_16x16x32_bf16(a[mi], b[ni], acc[mi][ni], 0, 0, 0);
  }

  // ---- fused el/er reduction (f32, from accumulators) ----
  const float* alh = al + blockIdx.y*HDIM;
  const float* arh = ar + blockIdx.y*HDIM;
  float alv[4], arv[4];
  #pragma unroll
  for(int ni = 0; ni < 4; ++ni){
    int d = wc*64 + ni*16 + l15;
    alv[ni] = alh[d]; arv[ni] = arh[d];
  }
  __shared__ float red[2][64][2];          // [wc][row][el/er]
  __shared__ int4 tile4[512];              // 64 x 128 fp8 bytes
  fp8t* tile8 = (fp8t*)tile4;

  #pragma unroll
  for(int mi = 0; mi < 2; ++mi){
    #pragma unroll
    for(int j = 0; j < 4; ++j){
      float pe = 0.f, pr = 0.f;
      #pragma unroll
      for(int ni = 0; ni < 4; ++ni){
        pe += acc[mi][ni][j]*alv[ni];
        pr += acc[mi][ni][j]*arv[ni];
      }
      for(int k = 8; k; k >>= 1){ pe += __shfl_xor(pe, k); pr += __shfl_xor(pr, k); }
      int row_l = wr*32 + mi*16 + lhi*4 + j;
      if(l15 == 0){ red[wc][row_l][0] = pe; red[wc][row_l][1] = pr; }
    }
  }
  #pragma unroll
  for(int mi = 0; mi < 2; ++mi)
    #pragma unroll
    for(int j = 0; j < 4; ++j){
      int row_l = wr*32 + mi*16 + lhi*4 + j;
      #pragma unroll
      for(int ni = 0; ni < 4; ++ni){
        float x = acc[mi][ni][j];
        unsigned bb = (unsigned)__builtin_amdgcn_cvt_pk_fp8_f32(x, x, 0, false) & 0xFFu;
        tile8[row_l*128 + wc*64 + ni*16 + l15] = (fp8t)bb;
      }
    }
  __syncthreads();

  if(tid < 64){
    int r = blockIdx.x*64 + tid;
    if(r < M){
      el4[(size_t)r*4 + blockIdx.y] = red[0][tid][0] + red[1][tid][0];
      er4[(size_t)r*4 + blockIdx.y] = red[0][tid][1] + red[1][tid][1];
    }
  }
  #pragma unroll
  for(int pass = 0; pass < 2; ++pass){
    int off = pass*4096 + tid*16;
    int row_l = off >> 7, col = off & 127;
    int r = blockIdx.x*64 + row_l;
    if(r < M)
      *reinterpret_cast<int4*>(feat8 + (size_t)r*(HEADS*HDIM) + blockIdx.y*HDIM + col) =
          tile4[off >> 4];
  }
}

// ---------------- softmax denominators (no-max: logits bounded) ----------------

__device__ __forceinline__ float lrelu(float x){ return x > 0.f ? x : NEG_SLOPE*x; }

template<int USE_LIST, int USE_MARK>
__global__ __launch_bounds__(256) void k_denom(const float* __restrict__ el4,
                                               const float* __restrict__ er4,
                                               const int* __restrict__ offs,
                                               const int* __restrict__ csr,
                                               const int* __restrict__ list,
                                               const unsigned char* __restrict__ mark,
                                               float* __restrict__ inv4, int total){
  int i = blockIdx.x*256 + threadIdx.x;
  if(i >= total) return;
  unsigned n = USE_LIST ? (unsigned)list[i] : (unsigned)i;
  if(n >= N_NODES) return;
  if(USE_MARK){ if(!mark[n]) return; }
  int o0 = offs[n];
  int deg = offs[n+1] - o0;
  if(deg < 0 || deg > N_EDGES) deg = 0;
  float4 erv = *reinterpret_cast<const float4*>(er4 + (size_t)n*4);
  float S0 = 0.f, S1 = 0.f, S2 = 0.f;
  for(int j = 0; j < deg; ++j){
    unsigned s = (unsigned)csr[o0 + j];
    if(s >= N_NODES) s = 0;
    float4 elv = *reinterpret_cast<const float4*>(el4 + (size_t)s*4);
    S0 += __expf(lrelu(elv.x + erv.x));
    S1 += __expf(lrelu(elv.y + erv.y));
    S2 += __expf(lrelu(elv.z + erv.z));
  }
  float4 iv;
  iv.x = (S0 > 0.f) ? 1.f/S0 : 0.f;
  iv.y = (S1 > 0.f) ? 1.f/S1 : 0.f;
  iv.z = (S2 > 0.f) ? 1.f/S2 : 0.f;
  iv.w = 0.f;
  *reinterpret_cast<float4*>(inv4 + (size_t)n*4) = iv;
}

// ---------------- aggregation: one block (128 thr) per dst node ----------------
// No reductions: alpha = exp(lrelu(el+er)) * inv_denom, straight accumulate.

#define AGG_CHUNK 128
#define SEQ_SZ   (BB*LL*4*HDIM)
#define SEQR_OFF SEQ_SZ
#define SEQR_SZ  (BB*LL*3*HDIM)
#define SH_OFF   (SEQ_SZ + SEQR_SZ)

template<int USE_LIST, int FUSED, int USE_MARK>
__global__ __launch_bounds__(128) void k_agg(const fp8t* __restrict__ feat8,
                                             const float* __restrict__ el4,
                                             const float* __restrict__ er4,
                                             const float* __restrict__ inv4,
                                             const float* __restrict__ bias,
                                             const int* __restrict__ offs,
                                             const int* __restrict__ csr,
                                             const int* __restrict__ list,
                                             const unsigned char* __restrict__ mark,
                                             bf16* __restrict__ h1,
                                             const float* __restrict__ ent_e,
                                             const float* __restrict__ rel_e,
                                             const float* __restrict__ glob,
                                             const float* __restrict__ sht,
                                             const int* __restrict__ s_tem,
                                             const int* __restrict__ r_tem,
                                             float* __restrict__ out){
  int bid = blockIdx.x;
  int n = USE_LIST ? list[bid] : bid;
  if(USE_MARK){ if(!mark[n]) return; }
  int tid = threadIdx.x;
  __shared__ float s_alpha[AGG_CHUNK][4];
  __shared__ int   s_src[AGG_CHUNK];
  __shared__ float s_facc[HEADS*HDIM];
  int o0 = offs[n];
  int deg = offs[n+1] - o0;
  if(deg < 0 || deg > N_EDGES) deg = 0;
  float4 erv = *reinterpret_cast<const float4*>(er4 + (size_t)n*4);
  float4 iv  = *reinterpret_cast<const float4*>(inv4 + (size_t)n*4);

  float a0 = 0.f, a1 = 0.f, a2 = 0.f, a3 = 0.f;
  int head = tid >> 5;
  for(int base = 0; base < deg; base += AGG_CHUNK){
    int cn = min(AGG_CHUNK, deg - base);
    if(base) __syncthreads();
    if(tid < cn){
      unsigned su = (unsigned)csr[o0 + base + tid];
      if(su >= N_NODES) su = 0;
      float4 elv = *reinterpret_cast<const float4*>(el4 + (size_t)su*4);
      s_src[tid] = (int)su;
      s_alpha[tid][0] = __expf(lrelu(elv.x + erv.x))*iv.x;
      s_alpha[tid][1] = __expf(lrelu(elv.y + erv.y))*iv.y;
      s_alpha[tid][2] = __expf(lrelu(elv.z + erv.z))*iv.z;
    }
    __syncthreads();
    if(tid < 96){
      for(int i = 0; i < cn; ++i){
        unsigned u = *reinterpret_cast<const unsigned*>(
            feat8 + (size_t)s_src[i]*(HEADS*HDIM) + tid*4);
        float al = s_alpha[i][head];
        a0 += al*__builtin_amdgcn_cvt_f32_fp8((int)u, 0);
        a1 += al*__builtin_amdgcn_cvt_f32_fp8((int)u, 1);
        a2 += al*__builtin_amdgcn_cvt_f32_fp8((int)u, 2);
        a3 += al*__builtin_amdgcn_cvt_f32_fp8((int)u, 3);
      }
    }
  }
  if(tid < 96){
    float4 w; w.x = a0; w.y = a1; w.z = a2; w.w = a3;
    *reinterpret_cast<float4*>(s_facc + tid*4) = w;
  }
  __syncthreads();
  float r = (s_facc[tid] + s_facc[HDIM + tid] + s_facc[2*HDIM + tid]
           + bias[tid] + bias[HDIM + tid] + bias[2*HDIM + tid])*(1.f/3.f);
  if(FUSED){
    int p = bid, b = p/LL, d = tid;
    float ent = ent_e[(size_t)s_tem[b]*HDIM + d];
    float rel = rel_e[(size_t)r_tem[b]*HDIM + d];
    float gl  = glob[(size_t)p*HDIM + d];
    size_t so = (size_t)p*(4*HDIM);
    out[so + d] = r; out[so + HDIM + d] = ent;
    out[so + 2*HDIM + d] = rel; out[so + 3*HDIM + d] = gl;
    size_t ro = SEQR_OFF + (size_t)p*(3*HDIM);
    out[ro + d] = r; out[ro + HDIM + d] = ent; out[ro + 2*HDIM + d] = gl;
    if(d == 0) out[SH_OFF + p] = sht[p];
  } else {
    h1[(size_t)n*HDIM + tid] = __float2bfloat16(r);
  }
}

// ---------------- launch ----------------

extern "C" void kernel_launch(void* const* d_in, const int* in_sizes, int n_in,
                              void* d_out, int out_size, void* d_ws, size_t ws_size,
                              hipStream_t stream){
  const float* node_feat = (const float*)d_in[0];
  const float* W1        = (const float*)d_in[1];
  const float* attn_l1   = (const float*)d_in[2];
  const float* attn_r1   = (const float*)d_in[3];
  const float* b1        = (const float*)d_in[4];
  const float* W2        = (const float*)d_in[5];
  const float* attn_l2   = (const float*)d_in[6];
  const float* attn_r2   = (const float*)d_in[7];
  const float* b2        = (const float*)d_in[8];
  const float* ent_emb   = (const float*)d_in[9];
  const float* rel_emb   = (const float*)d_in[10];
  const float* glob      = (const float*)d_in[11];
  const float* sht       = (const float*)d_in[12];
  const int*  e_src      = (const int*)d_in[13];
  const int*  e_dst      = (const int*)d_in[14];
  const int*  nid        = (const int*)d_in[15];
  const int*  s_tem      = (const int*)d_in[16];
  const int*  r_tem      = (const int*)d_in[17];
  float* out = (float*)d_out;

  char* ws = (char*)d_ws;
  size_t cur_off = 0;
  auto alloc = [&](size_t bytes)->char*{
    char* r = ws + cur_off;
    cur_off += (bytes + 255) & ~(size_t)255;
    return r;
  };
  fp8t*  feat8 = (fp8t*) alloc((size_t)N_NODES*HEADS*HDIM);      // 19.2 MB
  bf16*  h1    = (bf16*) alloc((size_t)N_NODES*HDIM*2);          // 12.8 MB
  float* el4   = (float*)alloc((size_t)N_NODES*4*4);             // 0.8 MB
  float* er4   = (float*)alloc((size_t)N_NODES*4*4);             // 0.8 MB
  float* inv4  = (float*)alloc((size_t)N_NODES*4*4);             // 0.8 MB
  bf16*  wt1   = (bf16*) alloc((size_t)HEADS*HDIM*HDIM*2);
  bf16*  wt2   = (bf16*) alloc((size_t)HEADS*HDIM*HDIM*2);
  int*   offs  = (int*)  alloc((size_t)(N_NODES+1)*4);
  int*   cnt   = (int*)  alloc((size_t)N_NODES*4);               // also cursor
  int*   bsum  = (int*)  alloc((size_t)SCAN_NB*4);
  unsigned char* mark = (unsigned char*)alloc((size_t)N_NODES);
  int*   csr   = (int*)  alloc((size_t)N_EDGES*4);

  // CSR build (shared by both layers); zero cnt + mark in one launch
  k_zero2<<<(N_NODES+255)/256, 256, 0, stream>>>(cnt, N_NODES,
                                                 (int*)mark, (N_NODES+3)/4);
  k_hist<<<(N_EDGES+255)/256, 256, 0, stream>>>(e_dst, cnt, N_EDGES);
  k_scan_part<<<SCAN_NB, 256, 0, stream>>>(cnt, bsum);
  k_scan_top<<<1, 64, 0, stream>>>(bsum, SCAN_NB);
  k_scan_write<<<SCAN_NB, 256, 0, stream>>>(cnt, bsum, offs);   // also zeroes cnt
  k_scatter<<<(N_EDGES+255)/256, 256, 0, stream>>>(e_src, e_dst, offs, cnt, csr, N_EDGES);
  k_mark<<<BB*LL, 64, 0, stream>>>(nid, offs, csr, mark);

  // weight transposes
  k_wt<<<(HEADS*HDIM*HDIM+255)/256, 256, 0, stream>>>(W1, wt1);
  k_wt<<<(HEADS*HDIM*HDIM+255)/256, 256, 0, stream>>>(W2, wt2);

  dim3 ggrid((N_NODES + 63)/64, HEADS);

  // Layer 1 (agg only for nodes layer 2 consumes)
  k_gemm<1><<<ggrid, 256, 0, stream>>>((const void*)node_feat, wt1, attn_l1, attn_r1,
                                       feat8, el4, er4, N_NODES);
  k_denom<0,1><<<(N_NODES+255)/256, 256, 0, stream>>>(el4, er4, offs, csr,
                                                      nullptr, mark, inv4, N_NODES);
  k_agg<0,0,1><<<N_NODES, 128, 0, stream>>>(feat8, el4, er4, inv4, b1, offs, csr,
                                            nullptr, mark, h1,
                                            nullptr, nullptr, nullptr, nullptr,
                                            nullptr, nullptr, nullptr);

  // Layer 2 (agg only over the nodes assemble needs; assemble fused in)
  k_gemm<0><<<ggrid, 256, 0, stream>>>((const void*)h1, wt2, attn_l2, attn_r2,
                                       feat8, el4, er4, N_NODES);
  k_denom<1,0><<<(BB*LL+255)/256, 256, 0, stream>>>(el4, er4, offs, csr,
                                                    nid, nullptr, inv4, BB*LL);
  k_agg<1,1,0><<<BB*LL, 128, 0, stream>>>(feat8, el4, er4, inv4, b2, offs, csr,
                                          nid, nullptr, nullptr,
                                          ent_emb, rel_emb, glob, sht,
                                          s_tem, r_tem, out);
}

// Round 9
// 197.413 us; speedup vs baseline: 1.1424x; 1.1424x over previous
//
#include <hip/hip_runtime.h>
#include <hip/hip_bf16.h>

#define N_NODES 50000
#define N_EDGES 500000
#define HDIM 128
#define HEADS 3
#define BB 512
#define LL 10
#define NEG_SLOPE 0.2f

typedef __hip_bfloat16 bf16;
typedef unsigned char fp8t;
typedef __bf16 v8bf __attribute__((ext_vector_type(8)));
typedef float f32x4 __attribute__((ext_vector_type(4)));

// ---------------- utility ----------------

__global__ void k_zero2(int* a, int na, int* b, int nb){
  int i = blockIdx.x*256 + threadIdx.x;
  if(i < na) a[i] = 0;
  if(i < nb) b[i] = 0;
}

__global__ void k_hist(const int* __restrict__ dst, int* __restrict__ cnt, int E){
  int e = blockIdx.x*256 + threadIdx.x;
  if(e < E) atomicAdd(&cnt[dst[e]], 1);
}

// f32 -> bf16, 8 elems/thread (n must be multiple of 8)
__global__ void k_cvt(const float* __restrict__ in, bf16* __restrict__ o, int n){
  int i = (blockIdx.x*256 + threadIdx.x)*8;
  if(i < n){
    f32x4 lo = *reinterpret_cast<const f32x4*>(in + i);
    f32x4 hi = *reinterpret_cast<const f32x4*>(in + i + 4);
    v8bf v;
    #pragma unroll
    for(int j = 0; j < 4; ++j){ v[j] = (__bf16)lo[j]; v[4+j] = (__bf16)hi[j]; }
    *reinterpret_cast<v8bf*>(o + i) = v;
  }
}

// ---------------- hierarchical scan: cnt[0..N) -> offs[0..N], offs[0]=0 ------

#define SCAN_TILE 2048
#define SCAN_NB ((N_NODES + SCAN_TILE - 1)/SCAN_TILE)   // 25

__global__ __launch_bounds__(256) void k_scan_part(const int* __restrict__ cnt,
                                                   int* __restrict__ bsum){
  int b = blockIdx.x, tid = threadIdx.x;
  int i0 = b*SCAN_TILE + tid*8;
  int s = 0;
  #pragma unroll
  for(int j = 0; j < 8; ++j){ int i = i0 + j; s += (i < N_NODES) ? cnt[i] : 0; }
  for(int m = 32; m; m >>= 1) s += __shfl_xor(s, m);
  __shared__ int ws[4];
  if((tid & 63) == 0) ws[tid >> 6] = s;
  __syncthreads();
  if(tid == 0) bsum[b] = ws[0] + ws[1] + ws[2] + ws[3];
}

__global__ __launch_bounds__(64) void k_scan_top(int* __restrict__ bsum, int nb){
  int tid = threadIdx.x;
  int v = (tid < nb) ? bsum[tid] : 0;
  for(int s = 1; s < 64; s <<= 1){
    int t = __shfl_up(v, s);
    if(tid >= s) v += t;
  }
  if(tid < nb) bsum[tid] = v;
}

__global__ __launch_bounds__(256) void k_scan_write(int* __restrict__ cnt,
                                                    const int* __restrict__ bsum,
                                                    int* __restrict__ offs){
  int b = blockIdx.x, tid = threadIdx.x;
  int lane = tid & 63, wv = tid >> 6;
  int i0 = b*SCAN_TILE + tid*8;
  int v[8]; int s = 0;
  #pragma unroll
  for(int j = 0; j < 8; ++j){
    int i = i0 + j;
    v[j] = (i < N_NODES) ? cnt[i] : 0;
    s += v[j];
  }
  #pragma unroll
  for(int j = 0; j < 8; ++j){ int i = i0 + j; if(i < N_NODES) cnt[i] = 0; }
  int incl = s;
  for(int sh = 1; sh < 64; sh <<= 1){
    int t = __shfl_up(incl, sh);
    if(lane >= sh) incl += t;
  }
  __shared__ int wtot[4];
  if(lane == 63) wtot[wv] = incl;
  __syncthreads();
  int woff = 0;
  for(int w = 0; w < wv; ++w) woff += wtot[w];
  int excl = woff + incl - s;
  int run = ((b > 0) ? bsum[b-1] : 0) + excl;
  #pragma unroll
  for(int j = 0; j < 8; ++j){
    int i = i0 + j;
    run += v[j];
    if(i < N_NODES) offs[i+1] = run;
  }
  if(b == 0 && tid == 0) offs[0] = 0;
}

__global__ void k_scatter(const int* __restrict__ src, const int* __restrict__ dst,
                          const int* __restrict__ offs, int* __restrict__ cur,
                          int* __restrict__ csr, int E){
  int e = blockIdx.x*256 + threadIdx.x;
  if(e < E){
    int d = dst[e];
    int p = offs[d] + atomicAdd(&cur[d], 1);
    if(p >= 0 && p < E) csr[p] = src[e];
  }
}

// ---------------- mark nodes whose h1 is actually consumed by layer 2 --------

__global__ __launch_bounds__(64) void k_mark(const int* __restrict__ nid,
                                             const int* __restrict__ offs,
                                             const int* __restrict__ csr,
                                             unsigned char* __restrict__ mark){
  unsigned n = (unsigned)nid[blockIdx.x];
  if(n >= N_NODES) return;
  if(threadIdx.x == 0) mark[n] = 1;
  int o0 = offs[n], o1 = offs[n+1];
  for(int j = o0 + (int)threadIdx.x; j < o1; j += 64){
    unsigned s = (unsigned)csr[j];
    if(s < N_NODES) mark[s] = 1;
  }
}

// ---------------- W transpose+convert: W f32 [128][384] -> Wt bf16 [384][128] -------

__global__ void k_wt(const float* __restrict__ W, bf16* __restrict__ Wt){
  int i = blockIdx.x*256 + threadIdx.x;
  if(i < HEADS*HDIM*HDIM){
    int n = i >> 7, k = i & 127;
    Wt[i] = __float2bfloat16(W[k*(HEADS*HDIM) + n]);
  }
}

// ---------------- GEMM + fused el/er + fp8 feat write ----------------
// All 24 fragment loads issued before the MFMA burst (latency hiding via MLP).

__global__ __launch_bounds__(256) void k_gemm(const bf16* __restrict__ A,
                                              const bf16* __restrict__ Wt,
                                              const float* __restrict__ al,
                                              const float* __restrict__ ar,
                                              fp8t* __restrict__ feat8,
                                              float* __restrict__ el4,
                                              float* __restrict__ er4, int M){
  int tid  = threadIdx.x;
  int wave = tid >> 6, lane = tid & 63;
  int wr = wave >> 1, wc = wave & 1;
  int row0 = blockIdx.x*64 + wr*32;
  int col0 = blockIdx.y*128 + wc*64;
  int l15 = lane & 15, lhi = lane >> 4;

  v8bf a[4][2], b[4][4];
  #pragma unroll
  for(int kk = 0; kk < 4; ++kk){
    int kb = kk*32 + lhi*8;
    #pragma unroll
    for(int mi = 0; mi < 2; ++mi){
      int r = row0 + mi*16 + l15;
      if(r >= M) r = M - 1;                 // clamp; stores are guarded
      a[kk][mi] = *reinterpret_cast<const v8bf*>(A + (size_t)r*HDIM + kb);
    }
    #pragma unroll
    for(int ni = 0; ni < 4; ++ni){
      int c = col0 + ni*16 + l15;
      b[kk][ni] = *reinterpret_cast<const v8bf*>(Wt + (size_t)c*HDIM + kb);
    }
  }

  f32x4 acc[2][4] = {};
  #pragma unroll
  for(int kk = 0; kk < 4; ++kk)
    #pragma unroll
    for(int mi = 0; mi < 2; ++mi)
      #pragma unroll
      for(int ni = 0; ni < 4; ++ni)
        acc[mi][ni] = __builtin_amdgcn_mfma_f32_16x16x32_bf16(a[kk][mi], b[kk][ni],
                                                              acc[mi][ni], 0, 0, 0);

  // ---- fused el/er reduction (f32, from accumulators) ----
  const float* alh = al + blockIdx.y*HDIM;
  const float* arh = ar + blockIdx.y*HDIM;
  float alv[4], arv[4];
  #pragma unroll
  for(int ni = 0; ni < 4; ++ni){
    int d = wc*64 + ni*16 + l15;
    alv[ni] = alh[d]; arv[ni] = arh[d];
  }
  __shared__ float red[2][64][2];          // [wc][row][el/er]
  __shared__ int4 tile4[512];              // 64 x 128 fp8 bytes
  fp8t* tile8 = (fp8t*)tile4;

  #pragma unroll
  for(int mi = 0; mi < 2; ++mi){
    #pragma unroll
    for(int j = 0; j < 4; ++j){
      float pe = 0.f, pr = 0.f;
      #pragma unroll
      for(int ni = 0; ni < 4; ++ni){
        pe += acc[mi][ni][j]*alv[ni];
        pr += acc[mi][ni][j]*arv[ni];
      }
      for(int k = 8; k; k >>= 1){ pe += __shfl_xor(pe, k); pr += __shfl_xor(pr, k); }
      int row_l = wr*32 + mi*16 + lhi*4 + j;
      if(l15 == 0){ red[wc][row_l][0] = pe; red[wc][row_l][1] = pr; }
    }
  }
  #pragma unroll
  for(int mi = 0; mi < 2; ++mi)
    #pragma unroll
    for(int j = 0; j < 4; ++j){
      int row_l = wr*32 + mi*16 + lhi*4 + j;
      #pragma unroll
      for(int ni = 0; ni < 4; ++ni){
        float x = acc[mi][ni][j];
        unsigned bb = (unsigned)__builtin_amdgcn_cvt_pk_fp8_f32(x, x, 0, false) & 0xFFu;
        tile8[row_l*128 + wc*64 + ni*16 + l15] = (fp8t)bb;
      }
    }
  __syncthreads();

  if(tid < 64){
    int r = blockIdx.x*64 + tid;
    if(r < M){
      el4[(size_t)r*4 + blockIdx.y] = red[0][tid][0] + red[1][tid][0];
      er4[(size_t)r*4 + blockIdx.y] = red[0][tid][1] + red[1][tid][1];
    }
  }
  #pragma unroll
  for(int pass = 0; pass < 2; ++pass){
    int off = pass*4096 + tid*16;
    int row_l = off >> 7, col = off & 127;
    int r = blockIdx.x*64 + row_l;
    if(r < M)
      *reinterpret_cast<int4*>(feat8 + (size_t)r*(HEADS*HDIM) + blockIdx.y*HDIM + col) =
          tile4[off >> 4];
  }
}

// ---------------- aggregation: one block (128 thr) per dst node ----------------
// Unnormalized exp weights + in-loop denominator accumulation (no-max softmax:
// logits bounded ~|3|, exact in f32). deg==0 -> zero aggregate + bias (ref match).

__device__ __forceinline__ float lrelu(float x){ return x > 0.f ? x : NEG_SLOPE*x; }

#define AGG_CHUNK 128
#define SEQ_SZ   (BB*LL*4*HDIM)
#define SEQR_OFF SEQ_SZ
#define SEQR_SZ  (BB*LL*3*HDIM)
#define SH_OFF   (SEQ_SZ + SEQR_SZ)

template<int USE_LIST, int FUSED, int USE_MARK>
__global__ __launch_bounds__(128) void k_agg(const fp8t* __restrict__ feat8,
                                             const float* __restrict__ el4,
                                             const float* __restrict__ er4,
                                             const float* __restrict__ bias,
                                             const int* __restrict__ offs,
                                             const int* __restrict__ csr,
                                             const int* __restrict__ list,
                                             const unsigned char* __restrict__ mark,
                                             bf16* __restrict__ h1,
                                             const float* __restrict__ ent_e,
                                             const float* __restrict__ rel_e,
                                             const float* __restrict__ glob,
                                             const float* __restrict__ sht,
                                             const int* __restrict__ s_tem,
                                             const int* __restrict__ r_tem,
                                             float* __restrict__ out){
  int bid = blockIdx.x;
  int n = USE_LIST ? list[bid] : bid;
  if(USE_MARK){ if(!mark[n]) return; }
  int tid = threadIdx.x;
  __shared__ float s_alpha[AGG_CHUNK][4];
  __shared__ int   s_src[AGG_CHUNK];
  __shared__ float s_facc[HEADS*HDIM];
  int o0 = offs[n];
  int deg = offs[n+1] - o0;
  if(deg < 0 || deg > N_EDGES) deg = 0;
  float4 erv = *reinterpret_cast<const float4*>(er4 + (size_t)n*4);

  float a0 = 0.f, a1 = 0.f, a2 = 0.f, a3 = 0.f, dh = 0.f;
  int head = tid >> 5;
  for(int base = 0; base < deg; base += AGG_CHUNK){
    int cn = min(AGG_CHUNK, deg - base);
    if(base) __syncthreads();
    if(tid < cn){
      unsigned su = (unsigned)csr[o0 + base + tid];
      if(su >= N_NODES) su = 0;
      float4 elv = *reinterpret_cast<const float4*>(el4 + (size_t)su*4);
      s_src[tid] = (int)su;
      s_alpha[tid][0] = __expf(lrelu(elv.x + erv.x));
      s_alpha[tid][1] = __expf(lrelu(elv.y + erv.y));
      s_alpha[tid][2] = __expf(lrelu(elv.z + erv.z));
    }
    __syncthreads();
    if(tid < 96){
      for(int i = 0; i < cn; ++i){
        unsigned u = *reinterpret_cast<const unsigned*>(
            feat8 + (size_t)s_src[i]*(HEADS*HDIM) + tid*4);
        float al = s_alpha[i][head];
        dh += al;
        a0 += al*__builtin_amdgcn_cvt_f32_fp8((int)u, 0);
        a1 += al*__builtin_amdgcn_cvt_f32_fp8((int)u, 1);
        a2 += al*__builtin_amdgcn_cvt_f32_fp8((int)u, 2);
        a3 += al*__builtin_amdgcn_cvt_f32_fp8((int)u, 3);
      }
    }
  }
  if(tid < 96){
    float inv = (dh > 0.f) ? 1.f/dh : 0.f;
    float4 w; w.x = a0*inv; w.y = a1*inv; w.z = a2*inv; w.w = a3*inv;
    *reinterpret_cast<float4*>(s_facc + tid*4) = w;
  }
  __syncthreads();
  float r = (s_facc[tid] + s_facc[HDIM + tid] + s_facc[2*HDIM + tid]
           + bias[tid] + bias[HDIM + tid] + bias[2*HDIM + tid])*(1.f/3.f);
  if(FUSED){
    int p = bid, b = p/LL, d = tid;
    float ent = ent_e[(size_t)s_tem[b]*HDIM + d];
    float rel = rel_e[(size_t)r_tem[b]*HDIM + d];
    float gl  = glob[(size_t)p*HDIM + d];
    size_t so = (size_t)p*(4*HDIM);
    out[so + d] = r; out[so + HDIM + d] = ent;
    out[so + 2*HDIM + d] = rel; out[so + 3*HDIM + d] = gl;
    size_t ro = SEQR_OFF + (size_t)p*(3*HDIM);
    out[ro + d] = r; out[ro + HDIM + d] = ent; out[ro + 2*HDIM + d] = gl;
    if(d == 0) out[SH_OFF + p] = sht[p];
  } else {
    h1[(size_t)n*HDIM + tid] = __float2bfloat16(r);
  }
}

// ---------------- launch ----------------

extern "C" void kernel_launch(void* const* d_in, const int* in_sizes, int n_in,
                              void* d_out, int out_size, void* d_ws, size_t ws_size,
                              hipStream_t stream){
  const float* node_feat = (const float*)d_in[0];
  const float* W1        = (const float*)d_in[1];
  const float* attn_l1   = (const float*)d_in[2];
  const float* attn_r1   = (const float*)d_in[3];
  const float* b1        = (const float*)d_in[4];
  const float* W2        = (const float*)d_in[5];
  const float* attn_l2   = (const float*)d_in[6];
  const float* attn_r2   = (const float*)d_in[7];
  const float* b2        = (const float*)d_in[8];
  const float* ent_emb   = (const float*)d_in[9];
  const float* rel_emb   = (const float*)d_in[10];
  const float* glob      = (const float*)d_in[11];
  const float* sht       = (const float*)d_in[12];
  const int*  e_src      = (const int*)d_in[13];
  const int*  e_dst      = (const int*)d_in[14];
  const int*  nid        = (const int*)d_in[15];
  const int*  s_tem      = (const int*)d_in[16];
  const int*  r_tem      = (const int*)d_in[17];
  float* out = (float*)d_out;

  char* ws = (char*)d_ws;
  size_t cur_off = 0;
  auto alloc = [&](size_t bytes)->char*{
    char* r = ws + cur_off;
    cur_off += (bytes + 255) & ~(size_t)255;
    return r;
  };
  fp8t*  feat8 = (fp8t*) alloc((size_t)N_NODES*HEADS*HDIM);      // 19.2 MB
  bf16*  nfb   = (bf16*) alloc((size_t)N_NODES*HDIM*2);          // 12.8 MB
  bf16*  h1    = (bf16*) alloc((size_t)N_NODES*HDIM*2);          // 12.8 MB
  float* el4   = (float*)alloc((size_t)N_NODES*4*4);             // 0.8 MB
  float* er4   = (float*)alloc((size_t)N_NODES*4*4);             // 0.8 MB
  bf16*  wt1   = (bf16*) alloc((size_t)HEADS*HDIM*HDIM*2);
  bf16*  wt2   = (bf16*) alloc((size_t)HEADS*HDIM*HDIM*2);
  int*   offs  = (int*)  alloc((size_t)(N_NODES+1)*4);
  int*   cnt   = (int*)  alloc((size_t)N_NODES*4);               // also cursor
  int*   bsum  = (int*)  alloc((size_t)SCAN_NB*4);
  unsigned char* mark = (unsigned char*)alloc((size_t)N_NODES);
  int*   csr   = (int*)  alloc((size_t)N_EDGES*4);

  // CSR build (shared by both layers); zero cnt + mark in one launch
  k_zero2<<<(N_NODES+255)/256, 256, 0, stream>>>(cnt, N_NODES,
                                                 (int*)mark, (N_NODES+3)/4);
  k_hist<<<(N_EDGES+255)/256, 256, 0, stream>>>(e_dst, cnt, N_EDGES);
  k_scan_part<<<SCAN_NB, 256, 0, stream>>>(cnt, bsum);
  k_scan_top<<<1, 64, 0, stream>>>(bsum, SCAN_NB);
  k_scan_write<<<SCAN_NB, 256, 0, stream>>>(cnt, bsum, offs);   // also zeroes cnt
  k_scatter<<<(N_EDGES+255)/256, 256, 0, stream>>>(e_src, e_dst, offs, cnt, csr, N_EDGES);
  k_mark<<<BB*LL, 64, 0, stream>>>(nid, offs, csr, mark);

  // weight transposes + node_feat f32->bf16
  k_wt<<<(HEADS*HDIM*HDIM+255)/256, 256, 0, stream>>>(W1, wt1);
  k_wt<<<(HEADS*HDIM*HDIM+255)/256, 256, 0, stream>>>(W2, wt2);
  k_cvt<<<(N_NODES*HDIM/8+255)/256, 256, 0, stream>>>(node_feat, nfb, N_NODES*HDIM);

  dim3 ggrid((N_NODES + 63)/64, HEADS);

  // Layer 1 (agg only for nodes layer 2 consumes)
  k_gemm<<<ggrid, 256, 0, stream>>>(nfb, wt1, attn_l1, attn_r1,
                                    feat8, el4, er4, N_NODES);
  k_agg<0,0,1><<<N_NODES, 128, 0, stream>>>(feat8, el4, er4, b1, offs, csr,
                                            nullptr, mark, h1,
                                            nullptr, nullptr, nullptr, nullptr,
                                            nullptr, nullptr, nullptr);

  // Layer 2 (agg only over the nodes assemble needs; assemble fused in)
  k_gemm<<<ggrid, 256, 0, stream>>>(h1, wt2, attn_l2, attn_r2,
                                    feat8, el4, er4, N_NODES);
  k_agg<1,1,0><<<BB*LL, 128, 0, stream>>>(feat8, el4, er4, b2, offs, csr,
                                          nid, nullptr, nullptr,
                                          ent_emb, rel_emb, glob, sht,
                                          s_tem, r_tem, out);
}